// Round 1
// baseline (436.750 us; speedup 1.0000x reference)
//
#include <hip/hip_runtime.h>

#define LEAKY(x) ((x) > 0.f ? (x) : 0.2f * (x))

// ---------------- CSR build ----------------

__global__ void degree_kernel(const int* __restrict__ dst, int* __restrict__ deg, int E) {
    int e = blockIdx.x * blockDim.x + threadIdx.x;
    if (e < E) atomicAdd(&deg[dst[e]], 1);
}

__global__ __launch_bounds__(1024) void scan_kernel(const int* __restrict__ deg,
                                                    int* __restrict__ off, int n) {
    __shared__ int wsum[16];
    int tid = threadIdx.x;
    int lane = tid & 63, wid = tid >> 6;
    int carry = 0;
    for (int base = 0; base < n; base += 1024) {
        int i = base + tid;
        int v = (i < n) ? deg[i] : 0;
        int x = v;
        #pragma unroll
        for (int d2 = 1; d2 < 64; d2 <<= 1) {
            int y = __shfl_up(x, d2);
            if (lane >= d2) x += y;
        }
        if (lane == 63) wsum[wid] = x;
        __syncthreads();
        if (tid < 16) {
            int s = wsum[tid];
            #pragma unroll
            for (int d2 = 1; d2 < 16; d2 <<= 1) {
                int y = __shfl_up(s, d2, 16);
                if (tid >= d2) s += y;
            }
            wsum[tid] = s;
        }
        __syncthreads();
        int wbase = wid ? wsum[wid - 1] : 0;
        int total = wsum[15];
        if (i < n) off[i] = carry + wbase + (x - v);  // exclusive
        carry += total;
        __syncthreads();  // protect wsum before next iteration
    }
    if (tid == 0) off[n] = carry;
}

__global__ void scatter_kernel(const int* __restrict__ src, const int* __restrict__ dst,
                               const int* __restrict__ off, int* __restrict__ cursor,
                               int* __restrict__ csr_src, int E) {
    int e = blockIdx.x * blockDim.x + threadIdx.x;
    if (e < E) {
        int d = dst[e];
        int p = atomicAdd(&cursor[d], 1);
        csr_src[off[d] + p] = src[e];
    }
}

// ---------------- Layer 1 GEMM: h1 = x @ W1  ([N,128]@[128,512]) ----------------

__global__ __launch_bounds__(256) void gemm1_kernel(const float* __restrict__ x,
                                                    const float* __restrict__ W,
                                                    float* __restrict__ h1, int N) {
    __shared__ __align__(16) float xs[64][68];
    __shared__ __align__(16) float ws[64][68];
    int row0 = blockIdx.x * 64, col0 = blockIdx.y * 64;
    int tid = threadIdx.x;
    int tx = tid & 15, ty = tid >> 4;
    float acc[4][4] = {};
    for (int kb = 0; kb < 2; ++kb) {
        int c4 = (tid & 15) * 4;
        int r = tid >> 4;
        #pragma unroll
        for (int i = 0; i < 4; ++i) {
            int rr = r + i * 16;
            int gr = row0 + rr;
            float4 v = make_float4(0.f, 0.f, 0.f, 0.f);
            if (gr < N) v = *(const float4*)(x + (size_t)gr * 128 + kb * 64 + c4);
            *(float4*)&xs[rr][c4] = v;
            float4 wv = *(const float4*)(W + (size_t)(kb * 64 + rr) * 512 + col0 + c4);
            *(float4*)&ws[rr][c4] = wv;
        }
        __syncthreads();
        #pragma unroll 8
        for (int k = 0; k < 64; ++k) {
            float a0 = xs[ty * 4 + 0][k], a1 = xs[ty * 4 + 1][k];
            float a2 = xs[ty * 4 + 2][k], a3 = xs[ty * 4 + 3][k];
            float4 b = *(const float4*)&ws[k][tx * 4];
            acc[0][0] += a0 * b.x; acc[0][1] += a0 * b.y; acc[0][2] += a0 * b.z; acc[0][3] += a0 * b.w;
            acc[1][0] += a1 * b.x; acc[1][1] += a1 * b.y; acc[1][2] += a1 * b.z; acc[1][3] += a1 * b.w;
            acc[2][0] += a2 * b.x; acc[2][1] += a2 * b.y; acc[2][2] += a2 * b.z; acc[2][3] += a2 * b.w;
            acc[3][0] += a3 * b.x; acc[3][1] += a3 * b.y; acc[3][2] += a3 * b.z; acc[3][3] += a3 * b.w;
        }
        __syncthreads();
    }
    #pragma unroll
    for (int i = 0; i < 4; ++i) {
        int gr = row0 + ty * 4 + i;
        if (gr < N)
            *(float4*)(h1 + (size_t)gr * 512 + col0 + tx * 4) =
                make_float4(acc[i][0], acc[i][1], acc[i][2], acc[i][3]);
    }
}

// ---------------- alpha_src1 / alpha_dst1 ----------------

__global__ __launch_bounds__(256) void alphas1_kernel(const float* __restrict__ h1,
                                                      const float* __restrict__ a_src,
                                                      const float* __restrict__ a_dst,
                                                      float* __restrict__ asrc1,
                                                      float* __restrict__ adst1, int N) {
    int n = (blockIdx.x * blockDim.x + threadIdx.x) >> 6;
    int lane = threadIdx.x & 63;
    if (n >= N) return;
    const float* hr = h1 + (size_t)n * 512;
    float4 v0 = *(const float4*)(hr + lane * 8);
    float4 v1 = *(const float4*)(hr + lane * 8 + 4);
    float4 s0 = *(const float4*)(a_src + lane * 8);
    float4 s1 = *(const float4*)(a_src + lane * 8 + 4);
    float4 d0 = *(const float4*)(a_dst + lane * 8);
    float4 d1 = *(const float4*)(a_dst + lane * 8 + 4);
    float ps = v0.x * s0.x + v0.y * s0.y + v0.z * s0.z + v0.w * s0.w +
               v1.x * s1.x + v1.y * s1.y + v1.z * s1.z + v1.w * s1.w;
    float pd = v0.x * d0.x + v0.y * d0.y + v0.z * d0.z + v0.w * d0.w +
               v1.x * d1.x + v1.y * d1.y + v1.z * d1.z + v1.w * d1.w;
    #pragma unroll
    for (int d2 = 1; d2 < 8; d2 <<= 1) {
        ps += __shfl_xor(ps, d2);
        pd += __shfl_xor(pd, d2);
    }
    if ((lane & 7) == 0) {
        asrc1[(size_t)n * 8 + (lane >> 3)] = ps;
        adst1[(size_t)n * 8 + (lane >> 3)] = pd;
    }
}

// ---------------- Layer 1 aggregation (one wave per node) ----------------

__global__ __launch_bounds__(256) void agg1_kernel(const float* __restrict__ h1,
                                                   const float* __restrict__ asrc,
                                                   const float* __restrict__ adst,
                                                   const int* __restrict__ off,
                                                   const int* __restrict__ csr_src,
                                                   const float* __restrict__ b1,
                                                   float* __restrict__ out1, int N) {
    int n = (blockIdx.x * blockDim.x + threadIdx.x) >> 6;
    int lane = threadIdx.x & 63;
    if (n >= N) return;
    float ad[8];
    {
        float4 t0 = *(const float4*)(adst + (size_t)n * 8);
        float4 t1 = *(const float4*)(adst + (size_t)n * 8 + 4);
        ad[0] = t0.x; ad[1] = t0.y; ad[2] = t0.z; ad[3] = t0.w;
        ad[4] = t1.x; ad[5] = t1.y; ad[6] = t1.z; ad[7] = t1.w;
    }
    float d[8], acc[8];
    {   // self-loop
        float4 s0 = *(const float4*)(asrc + (size_t)n * 8);
        float4 s1 = *(const float4*)(asrc + (size_t)n * 8 + 4);
        float es[8] = {s0.x + ad[0], s0.y + ad[1], s0.z + ad[2], s0.w + ad[3],
                       s1.x + ad[4], s1.y + ad[5], s1.z + ad[6], s1.w + ad[7]};
        const float* hrow = h1 + (size_t)n * 512;
        #pragma unroll
        for (int k = 0; k < 8; ++k) {
            float e = LEAKY(es[k]);
            float w = __expf(e);
            d[k] = w;
            acc[k] = w * hrow[k * 64 + lane];
        }
    }
    int t0e = off[n], t1e = off[n + 1];
    for (int t = t0e; t < t1e; ++t) {
        int s = csr_src[t];
        float4 s0 = *(const float4*)(asrc + (size_t)s * 8);
        float4 s1 = *(const float4*)(asrc + (size_t)s * 8 + 4);
        float es[8] = {s0.x + ad[0], s0.y + ad[1], s0.z + ad[2], s0.w + ad[3],
                       s1.x + ad[4], s1.y + ad[5], s1.z + ad[6], s1.w + ad[7]};
        const float* hrow = h1 + (size_t)s * 512;
        #pragma unroll
        for (int k = 0; k < 8; ++k) {
            float e = LEAKY(es[k]);
            float w = __expf(e);
            d[k] += w;
            acc[k] += w * hrow[k * 64 + lane];
        }
    }
    #pragma unroll
    for (int k = 0; k < 8; ++k) {
        float o = acc[k] / (d[k] + 1e-16f) + b1[k * 64 + lane];
        out1[(size_t)n * 512 + k * 64 + lane] = o > 0.f ? o : 0.f;  // ReLU
    }
}

// ---------------- Layer 2 GEMM + alpha2: h2 = out1 @ W2 ([N,512]@[512,8]) ----------------

__global__ __launch_bounds__(512) void gemm2_kernel(const float* __restrict__ out1,
                                                    const float* __restrict__ W2,
                                                    const float* __restrict__ a_src2,
                                                    const float* __restrict__ a_dst2,
                                                    float* __restrict__ h2,
                                                    float* __restrict__ as2,
                                                    float* __restrict__ ad2, int N) {
    __shared__ __align__(16) float xs[64][65];
    __shared__ __align__(16) float w2s[512 * 8];
    int tid = threadIdx.x;
    int node0 = blockIdx.x * 64;
    // load W2 (16 KB)
    for (int i = tid; i < 1024; i += 512) ((float4*)w2s)[i] = ((const float4*)W2)[i];
    int r = tid >> 3, c = tid & 7;
    float acc = 0.f;
    for (int kb = 0; kb < 8; ++kb) {
        __syncthreads();
        #pragma unroll
        for (int li = 0; li < 2; ++li) {
            int f4 = tid + li * 512;          // 0..1023
            int rr = f4 >> 4, c4 = (f4 & 15) * 4;
            int gr = node0 + rr;
            float4 v = make_float4(0.f, 0.f, 0.f, 0.f);
            if (gr < N) v = *(const float4*)(out1 + (size_t)gr * 512 + kb * 64 + c4);
            *(float4*)&xs[rr][c4] = v;
        }
        __syncthreads();
        #pragma unroll 8
        for (int k = 0; k < 64; ++k)
            acc += xs[r][k] * w2s[(kb * 64 + k) * 8 + c];
    }
    // acc = h2[node0+r][c]
    float pa = acc * a_src2[c];
    float pb = acc * a_dst2[c];
    #pragma unroll
    for (int d2 = 1; d2 < 8; d2 <<= 1) {
        pa += __shfl_xor(pa, d2);
        pb += __shfl_xor(pb, d2);
    }
    int n = node0 + r;
    if (n < N) {
        h2[(size_t)n * 8 + c] = acc;
        if (c == 0) { as2[n] = pa; ad2[n] = pb; }
    }
}

// ---------------- Layer 2 aggregation (8 lanes per node) + bias ----------------

__global__ __launch_bounds__(256) void agg2_kernel(const float* __restrict__ h2,
                                                   const float* __restrict__ as2,
                                                   const float* __restrict__ ad2,
                                                   const int* __restrict__ off,
                                                   const int* __restrict__ csr_src,
                                                   const float* __restrict__ b2,
                                                   float* __restrict__ out, int N) {
    int gid = blockIdx.x * blockDim.x + threadIdx.x;
    int n = gid >> 3, c = gid & 7;
    if (n >= N) return;
    float adn = ad2[n];
    float e = as2[n] + adn;
    e = LEAKY(e);
    float w = __expf(e);
    float d = w;
    float acc = w * h2[(size_t)n * 8 + c];
    int t0e = off[n], t1e = off[n + 1];
    for (int t = t0e; t < t1e; ++t) {
        int s = csr_src[t];
        float ee = as2[s] + adn;
        ee = LEAKY(ee);
        float ws = __expf(ee);
        d += ws;
        acc += ws * h2[(size_t)s * 8 + c];
    }
    out[(size_t)n * 8 + c] = acc / (d + 1e-16f) + b2[c];
}

// ---------------- launcher ----------------

extern "C" void kernel_launch(void* const* d_in, const int* in_sizes, int n_in,
                              void* d_out, int out_size, void* d_ws, size_t ws_size,
                              hipStream_t stream) {
    const float* x      = (const float*)d_in[0];
    const int*   ei     = (const int*)d_in[1];
    const float* W1     = (const float*)d_in[2];
    const float* a_src1 = (const float*)d_in[3];
    const float* a_dst1 = (const float*)d_in[4];
    const float* b1     = (const float*)d_in[5];
    const float* W2     = (const float*)d_in[6];
    const float* a_src2 = (const float*)d_in[7];
    const float* a_dst2 = (const float*)d_in[8];
    const float* b2     = (const float*)d_in[9];

    int N = in_sizes[0] / 128;
    int E = in_sizes[1] / 2;
    const int* src = ei;
    const int* dst = ei + E;

    char* w = (char*)d_ws;
    size_t o = 0;
    auto alloc = [&](size_t bytes) {
        void* p = w + o;
        o = (o + bytes + 255) & ~(size_t)255;
        return p;
    };
    float* h1     = (float*)alloc((size_t)N * 512 * 4);
    float* out1   = (float*)alloc((size_t)N * 512 * 4);
    float* asrc1  = (float*)alloc((size_t)N * 8 * 4);
    float* adst1  = (float*)alloc((size_t)N * 8 * 4);
    float* h2     = (float*)alloc((size_t)N * 8 * 4);
    float* as2    = (float*)alloc((size_t)N * 4);
    float* ad2    = (float*)alloc((size_t)N * 4);
    int*   deg    = (int*)alloc((size_t)N * 4);
    int*   offb   = (int*)alloc((size_t)(N + 1) * 4);
    int*   cursor = (int*)alloc((size_t)N * 4);
    int*   csrs   = (int*)alloc((size_t)E * 4);

    hipMemsetAsync(deg, 0, (size_t)N * 4, stream);
    hipMemsetAsync(cursor, 0, (size_t)N * 4, stream);

    degree_kernel<<<(E + 255) / 256, 256, 0, stream>>>(dst, deg, E);
    scan_kernel<<<1, 1024, 0, stream>>>(deg, offb, N);
    scatter_kernel<<<(E + 255) / 256, 256, 0, stream>>>(src, dst, offb, cursor, csrs, E);

    gemm1_kernel<<<dim3((N + 63) / 64, 8), 256, 0, stream>>>(x, W1, h1, N);
    alphas1_kernel<<<((size_t)N * 64 + 255) / 256, 256, 0, stream>>>(h1, a_src1, a_dst1, asrc1, adst1, N);
    agg1_kernel<<<((size_t)N * 64 + 255) / 256, 256, 0, stream>>>(h1, asrc1, adst1, offb, csrs, b1, out1, N);

    gemm2_kernel<<<(N + 63) / 64, 512, 0, stream>>>(out1, W2, a_src2, a_dst2, h2, as2, ad2, N);
    agg2_kernel<<<((size_t)N * 8 + 255) / 256, 256, 0, stream>>>(h2, as2, ad2, offb, csrs, b2, (float*)d_out, N);
}

// Round 2
// 348.676 us; speedup vs baseline: 1.2526x; 1.2526x over previous
//
#include <hip/hip_runtime.h>
#include <stdint.h>

#define LEAKY(x) ((x) > 0.f ? (x) : 0.2f * (x))

__device__ inline float2 bf2_to_f2(uint32_t p) {
    return make_float2(__uint_as_float(p << 16), __uint_as_float(p & 0xffff0000u));
}
__device__ inline uint32_t pack_bf2(float x, float y) {
    uint32_t xb = __float_as_uint(x), yb = __float_as_uint(y);
    xb += 0x7fff + ((xb >> 16) & 1);   // RNE to bf16
    yb += 0x7fff + ((yb >> 16) & 1);
    return (xb >> 16) | (yb & 0xffff0000u);
}

// ---------------- CSR build ----------------

__global__ void degree_kernel(const int* __restrict__ dst, int* __restrict__ deg, int E) {
    int e = blockIdx.x * blockDim.x + threadIdx.x;
    if (e < E) atomicAdd(&deg[dst[e]], 1);
}

__global__ __launch_bounds__(1024) void scan_kernel(const int* __restrict__ deg,
                                                    int* __restrict__ off, int n) {
    __shared__ int wsum[16];
    int tid = threadIdx.x;
    int lane = tid & 63, wid = tid >> 6;
    int carry = 0;
    for (int base = 0; base < n; base += 1024) {
        int i = base + tid;
        int v = (i < n) ? deg[i] : 0;
        int x = v;
        #pragma unroll
        for (int d2 = 1; d2 < 64; d2 <<= 1) {
            int y = __shfl_up(x, d2);
            if (lane >= d2) x += y;
        }
        if (lane == 63) wsum[wid] = x;
        __syncthreads();
        if (tid < 16) {
            int s = wsum[tid];
            #pragma unroll
            for (int d2 = 1; d2 < 16; d2 <<= 1) {
                int y = __shfl_up(s, d2, 16);
                if (tid >= d2) s += y;
            }
            wsum[tid] = s;
        }
        __syncthreads();
        int wbase = wid ? wsum[wid - 1] : 0;
        int total = wsum[15];
        if (i < n) off[i] = carry + wbase + (x - v);  // exclusive
        carry += total;
        __syncthreads();
    }
    if (tid == 0) off[n] = carry;
}

__global__ void scatter_kernel(const int* __restrict__ src, const int* __restrict__ dst,
                               const int* __restrict__ off, int* __restrict__ cursor,
                               int* __restrict__ csr_src, int E) {
    int e = blockIdx.x * blockDim.x + threadIdx.x;
    if (e < E) {
        int d = dst[e];
        int p = atomicAdd(&cursor[d], 1);
        csr_src[off[d] + p] = src[e];
    }
}

// ------- Layer 1 GEMM: h1 = x @ W1 ([N,128]@[128,512]) + fused alpha dots -------
// blockIdx.y == head (64-col block). h1 written as bf16 (uint32 pairs).

__global__ __launch_bounds__(256) void gemm1_kernel(const float* __restrict__ x,
                                                    const float* __restrict__ W,
                                                    const float* __restrict__ a_src,
                                                    const float* __restrict__ a_dst,
                                                    uint32_t* __restrict__ h1,
                                                    float* __restrict__ asrc1,
                                                    float* __restrict__ adst1, int N) {
    __shared__ __align__(16) float xs[64][68];
    __shared__ __align__(16) float ws[64][68];
    int row0 = blockIdx.x * 64;
    int head = blockIdx.y;
    int col0 = head * 64;
    int tid = threadIdx.x;
    int tx = tid & 15, ty = tid >> 4;
    float acc[4][4] = {};
    for (int kb = 0; kb < 2; ++kb) {
        int c4 = (tid & 15) * 4;
        int r = tid >> 4;
        #pragma unroll
        for (int i = 0; i < 4; ++i) {
            int rr = r + i * 16;
            int gr = row0 + rr;
            float4 v = make_float4(0.f, 0.f, 0.f, 0.f);
            if (gr < N) v = *(const float4*)(x + (size_t)gr * 128 + kb * 64 + c4);
            *(float4*)&xs[rr][c4] = v;
            float4 wv = *(const float4*)(W + (size_t)(kb * 64 + rr) * 512 + col0 + c4);
            *(float4*)&ws[rr][c4] = wv;
        }
        __syncthreads();
        #pragma unroll 8
        for (int k = 0; k < 64; ++k) {
            float a0 = xs[ty * 4 + 0][k], a1 = xs[ty * 4 + 1][k];
            float a2 = xs[ty * 4 + 2][k], a3 = xs[ty * 4 + 3][k];
            float4 b = *(const float4*)&ws[k][tx * 4];
            acc[0][0] += a0 * b.x; acc[0][1] += a0 * b.y; acc[0][2] += a0 * b.z; acc[0][3] += a0 * b.w;
            acc[1][0] += a1 * b.x; acc[1][1] += a1 * b.y; acc[1][2] += a1 * b.z; acc[1][3] += a1 * b.w;
            acc[2][0] += a2 * b.x; acc[2][1] += a2 * b.y; acc[2][2] += a2 * b.z; acc[2][3] += a2 * b.w;
            acc[3][0] += a3 * b.x; acc[3][1] += a3 * b.y; acc[3][2] += a3 * b.z; acc[3][3] += a3 * b.w;
        }
        __syncthreads();
    }
    float4 as4 = *(const float4*)(a_src + (size_t)head * 64 + tx * 4);
    float4 ad4 = *(const float4*)(a_dst + (size_t)head * 64 + tx * 4);
    #pragma unroll
    for (int i = 0; i < 4; ++i) {
        int gr = row0 + ty * 4 + i;
        float ps = acc[i][0] * as4.x + acc[i][1] * as4.y + acc[i][2] * as4.z + acc[i][3] * as4.w;
        float pd = acc[i][0] * ad4.x + acc[i][1] * ad4.y + acc[i][2] * ad4.z + acc[i][3] * ad4.w;
        #pragma unroll
        for (int m = 1; m < 16; m <<= 1) { ps += __shfl_xor(ps, m); pd += __shfl_xor(pd, m); }
        if (gr < N) {
            uint2 pk;
            pk.x = pack_bf2(acc[i][0], acc[i][1]);
            pk.y = pack_bf2(acc[i][2], acc[i][3]);
            *(uint2*)(h1 + (size_t)gr * 256 + head * 32 + tx * 2) = pk;
            if (tx == 0) {
                asrc1[(size_t)gr * 8 + head] = ps;
                adst1[(size_t)gr * 8 + head] = pd;
            }
        }
    }
}

// ---------------- Layer 1 aggregation (one wave per node, bf16 h1) ----------------
// uint index u = k*64+lane -> channels (2u, 2u+1), head = 2k + (lane>>5).

__global__ __launch_bounds__(256) void agg1_kernel(const uint32_t* __restrict__ h1,
                                                   const float* __restrict__ asrc,
                                                   const float* __restrict__ adst,
                                                   const int* __restrict__ off,
                                                   const int* __restrict__ csr_src,
                                                   const float* __restrict__ b1,
                                                   uint32_t* __restrict__ out1, int N) {
    int n = (blockIdx.x * blockDim.x + threadIdx.x) >> 6;
    int lane = threadIdx.x & 63;
    if (n >= N) return;
    int hi = lane >> 5;
    int cl = (lane & 31) * 2;
    float ad[4], d[4];
    float2 acc[4];
    #pragma unroll
    for (int k = 0; k < 4; ++k) ad[k] = adst[(size_t)n * 8 + 2 * k + hi];
    {   // self loop
        const uint32_t* hrow = h1 + (size_t)n * 256;
        #pragma unroll
        for (int k = 0; k < 4; ++k) {
            float e = asrc[(size_t)n * 8 + 2 * k + hi] + ad[k];
            float w = __expf(LEAKY(e));
            d[k] = w;
            float2 hv = bf2_to_f2(hrow[k * 64 + lane]);
            acc[k].x = w * hv.x;
            acc[k].y = w * hv.y;
        }
    }
    int t = off[n], tend = off[n + 1];
    for (; t + 1 < tend; t += 2) {
        int s0 = csr_src[t], s1 = csr_src[t + 1];
        const uint32_t* hr0 = h1 + (size_t)s0 * 256;
        const uint32_t* hr1 = h1 + (size_t)s1 * 256;
        uint32_t p0[4], p1[4];
        float e0[4], e1[4];
        #pragma unroll
        for (int k = 0; k < 4; ++k) { p0[k] = hr0[k * 64 + lane]; p1[k] = hr1[k * 64 + lane]; }
        #pragma unroll
        for (int k = 0; k < 4; ++k) {
            e0[k] = asrc[(size_t)s0 * 8 + 2 * k + hi] + ad[k];
            e1[k] = asrc[(size_t)s1 * 8 + 2 * k + hi] + ad[k];
        }
        #pragma unroll
        for (int k = 0; k < 4; ++k) {
            float w0 = __expf(LEAKY(e0[k]));
            float w1 = __expf(LEAKY(e1[k]));
            d[k] += w0 + w1;
            float2 h0 = bf2_to_f2(p0[k]), h1v = bf2_to_f2(p1[k]);
            acc[k].x += w0 * h0.x + w1 * h1v.x;
            acc[k].y += w0 * h0.y + w1 * h1v.y;
        }
    }
    if (t < tend) {
        int s = csr_src[t];
        const uint32_t* hr = h1 + (size_t)s * 256;
        #pragma unroll
        for (int k = 0; k < 4; ++k) {
            float e = asrc[(size_t)s * 8 + 2 * k + hi] + ad[k];
            float w = __expf(LEAKY(e));
            d[k] += w;
            float2 hv = bf2_to_f2(hr[k * 64 + lane]);
            acc[k].x += w * hv.x;
            acc[k].y += w * hv.y;
        }
    }
    #pragma unroll
    for (int k = 0; k < 4; ++k) {
        int head = 2 * k + hi;
        float2 bv = *(const float2*)(b1 + head * 64 + cl);
        float inv = 1.f / (d[k] + 1e-16f);
        float ox = fmaxf(acc[k].x * inv + bv.x, 0.f);
        float oy = fmaxf(acc[k].y * inv + bv.y, 0.f);
        out1[(size_t)n * 256 + k * 64 + lane] = pack_bf2(ox, oy);
    }
}

// ------- Layer 2 GEMM + alpha2: h2 = out1 @ W2 ([N,512(bf16)]@[512,8]) -------

__global__ __launch_bounds__(512) void gemm2_kernel(const uint32_t* __restrict__ out1,
                                                    const float* __restrict__ W2,
                                                    const float* __restrict__ a_src2,
                                                    const float* __restrict__ a_dst2,
                                                    float* __restrict__ h2,
                                                    float* __restrict__ as2,
                                                    float* __restrict__ ad2, int N) {
    __shared__ __align__(16) float xs[64][65];
    __shared__ __align__(16) float w2s[512 * 8];
    int tid = threadIdx.x;
    int node0 = blockIdx.x * 64;
    for (int i = tid; i < 1024; i += 512) ((float4*)w2s)[i] = ((const float4*)W2)[i];
    int r = tid >> 3, c = tid & 7;
    float acc = 0.f;
    for (int kb = 0; kb < 8; ++kb) {
        __syncthreads();
        #pragma unroll
        for (int li = 0; li < 2; ++li) {
            int f4 = tid + li * 512;              // 0..1023
            int rr = f4 >> 4, q = f4 & 15;        // quad of 4 channels
            int gr = node0 + rr;
            uint2 pv = make_uint2(0u, 0u);
            if (gr < N) pv = *(const uint2*)(out1 + (size_t)gr * 256 + kb * 32 + q * 2);
            float2 v0 = bf2_to_f2(pv.x), v1 = bf2_to_f2(pv.y);
            float* dsti = &xs[rr][q * 4];
            dsti[0] = v0.x; dsti[1] = v0.y; dsti[2] = v1.x; dsti[3] = v1.y;
        }
        __syncthreads();
        #pragma unroll 8
        for (int k = 0; k < 64; ++k)
            acc += xs[r][k] * w2s[(kb * 64 + k) * 8 + c];
    }
    float pa = acc * a_src2[c];
    float pb = acc * a_dst2[c];
    #pragma unroll
    for (int d2 = 1; d2 < 8; d2 <<= 1) {
        pa += __shfl_xor(pa, d2);
        pb += __shfl_xor(pb, d2);
    }
    int n = node0 + r;
    if (n < N) {
        h2[(size_t)n * 8 + c] = acc;
        if (c == 0) { as2[n] = pa; ad2[n] = pb; }
    }
}

// ---------------- Layer 2 aggregation (8 lanes per node) + bias ----------------

__global__ __launch_bounds__(256) void agg2_kernel(const float* __restrict__ h2,
                                                   const float* __restrict__ as2,
                                                   const float* __restrict__ ad2,
                                                   const int* __restrict__ off,
                                                   const int* __restrict__ csr_src,
                                                   const float* __restrict__ b2,
                                                   float* __restrict__ out, int N) {
    int gid = blockIdx.x * blockDim.x + threadIdx.x;
    int n = gid >> 3, c = gid & 7;
    if (n >= N) return;
    float adn = ad2[n];
    float e = LEAKY(as2[n] + adn);
    float w = __expf(e);
    float d = w;
    float acc = w * h2[(size_t)n * 8 + c];
    int t0e = off[n], t1e = off[n + 1];
    for (int t = t0e; t < t1e; ++t) {
        int s = csr_src[t];
        float ee = LEAKY(as2[s] + adn);
        float ws = __expf(ee);
        d += ws;
        acc += ws * h2[(size_t)s * 8 + c];
    }
    out[(size_t)n * 8 + c] = acc / (d + 1e-16f) + b2[c];
}

// ---------------- launcher ----------------

extern "C" void kernel_launch(void* const* d_in, const int* in_sizes, int n_in,
                              void* d_out, int out_size, void* d_ws, size_t ws_size,
                              hipStream_t stream) {
    const float* x      = (const float*)d_in[0];
    const int*   ei     = (const int*)d_in[1];
    const float* W1     = (const float*)d_in[2];
    const float* a_src1 = (const float*)d_in[3];
    const float* a_dst1 = (const float*)d_in[4];
    const float* b1     = (const float*)d_in[5];
    const float* W2     = (const float*)d_in[6];
    const float* a_src2 = (const float*)d_in[7];
    const float* a_dst2 = (const float*)d_in[8];
    const float* b2     = (const float*)d_in[9];

    int N = in_sizes[0] / 128;
    int E = in_sizes[1] / 2;
    const int* src = ei;
    const int* dst = ei + E;

    char* w = (char*)d_ws;
    size_t o = 0;
    auto alloc = [&](size_t bytes) {
        void* p = w + o;
        o = (o + bytes + 255) & ~(size_t)255;
        return p;
    };
    uint32_t* h1     = (uint32_t*)alloc((size_t)N * 256 * 4);  // bf16 [N,512]
    uint32_t* out1   = (uint32_t*)alloc((size_t)N * 256 * 4);  // bf16 [N,512]
    float*    asrc1  = (float*)alloc((size_t)N * 8 * 4);
    float*    adst1  = (float*)alloc((size_t)N * 8 * 4);
    float*    h2     = (float*)alloc((size_t)N * 8 * 4);
    float*    as2    = (float*)alloc((size_t)N * 4);
    float*    ad2    = (float*)alloc((size_t)N * 4);
    int*      deg    = (int*)alloc((size_t)N * 4);
    int*      offb   = (int*)alloc((size_t)(N + 1) * 4);
    int*      cursor = (int*)alloc((size_t)N * 4);
    int*      csrs   = (int*)alloc((size_t)E * 4);

    hipMemsetAsync(deg, 0, (size_t)N * 4, stream);
    hipMemsetAsync(cursor, 0, (size_t)N * 4, stream);

    degree_kernel<<<(E + 255) / 256, 256, 0, stream>>>(dst, deg, E);
    scan_kernel<<<1, 1024, 0, stream>>>(deg, offb, N);
    scatter_kernel<<<(E + 255) / 256, 256, 0, stream>>>(src, dst, offb, cursor, csrs, E);

    gemm1_kernel<<<dim3((N + 63) / 64, 8), 256, 0, stream>>>(x, W1, a_src1, a_dst1, h1, asrc1, adst1, N);
    agg1_kernel<<<((size_t)N * 64 + 255) / 256, 256, 0, stream>>>(h1, asrc1, adst1, offb, csrs, b1, out1, N);

    gemm2_kernel<<<(N + 63) / 64, 512, 0, stream>>>(out1, W2, a_src2, a_dst2, h2, as2, ad2, N);
    agg2_kernel<<<((size_t)N * 8 + 255) / 256, 256, 0, stream>>>(h2, as2, ad2, offb, csrs, b2, (float*)d_out, N);
}

// Round 4
// 293.710 us; speedup vs baseline: 1.4870x; 1.1871x over previous
//
#include <hip/hip_runtime.h>
#include <stdint.h>

#define LEAKY(x) ((x) > 0.f ? (x) : 0.2f * (x))

typedef short bf16x8 __attribute__((ext_vector_type(8)));
typedef float f32x4 __attribute__((ext_vector_type(4)));

__device__ inline float2 bf2_to_f2(uint32_t p) {
    return make_float2(__uint_as_float(p << 16), __uint_as_float(p & 0xffff0000u));
}
__device__ inline uint32_t pack_bf2(float x, float y) {
    uint32_t xb = __float_as_uint(x), yb = __float_as_uint(y);
    xb += 0x7fff + ((xb >> 16) & 1);   // RNE to bf16
    yb += 0x7fff + ((yb >> 16) & 1);
    return (xb >> 16) | (yb & 0xffff0000u);
}
__device__ inline ushort to_bf16(float v) {
    uint32_t b = __float_as_uint(v);
    b += 0x7fff + ((b >> 16) & 1);
    return (ushort)(b >> 16);
}

// ---------------- CSR build ----------------

__global__ void degree_kernel(const int* __restrict__ dst, int* __restrict__ deg, int E) {
    int e = blockIdx.x * blockDim.x + threadIdx.x;
    if (e < E) atomicAdd(&deg[dst[e]], 1);
}

__global__ __launch_bounds__(1024) void scan_kernel(const int* __restrict__ deg,
                                                    int* __restrict__ off, int n) {
    __shared__ int wsum[16];
    int tid = threadIdx.x;
    int lane = tid & 63, wid = tid >> 6;
    int carry = 0;
    for (int base = 0; base < n; base += 1024) {
        int i = base + tid;
        int v = (i < n) ? deg[i] : 0;
        int x = v;
        #pragma unroll
        for (int d2 = 1; d2 < 64; d2 <<= 1) {
            int y = __shfl_up(x, d2);
            if (lane >= d2) x += y;
        }
        if (lane == 63) wsum[wid] = x;
        __syncthreads();
        if (tid < 16) {
            int s = wsum[tid];
            #pragma unroll
            for (int d2 = 1; d2 < 16; d2 <<= 1) {
                int y = __shfl_up(s, d2, 16);
                if (tid >= d2) s += y;
            }
            wsum[tid] = s;
        }
        __syncthreads();
        int wbase = wid ? wsum[wid - 1] : 0;
        int total = wsum[15];
        if (i < n) off[i] = carry + wbase + (x - v);  // exclusive
        carry += total;
        __syncthreads();
    }
    if (tid == 0) off[n] = carry;
}

__global__ void scatter_kernel(const int* __restrict__ src, const int* __restrict__ dst,
                               const int* __restrict__ off, int* __restrict__ cursor,
                               int* __restrict__ csr_src, int E) {
    int e = blockIdx.x * blockDim.x + threadIdx.x;
    if (e < E) {
        int d = dst[e];
        int p = atomicAdd(&cursor[d], 1);
        csr_src[off[d] + p] = src[e];
    }
}

// ---------------- W1 -> W1T bf16 [512][128] ----------------

__global__ __launch_bounds__(256) void w1t_kernel(const float* __restrict__ W,
                                                  ushort* __restrict__ WT) {
    int c = blockIdx.x * 64 + (threadIdx.x & 63);
    int k0 = (threadIdx.x >> 6) * 32;
    #pragma unroll
    for (int j = 0; j < 32; ++j)
        WT[(size_t)c * 128 + k0 + j] = to_bf16(W[(size_t)(k0 + j) * 512 + c]);
}

// ------- Layer 1 GEMM via MFMA: h1 = x @ W1 ([N,128]@[128,512]) + fused alphas -------
// 128x128 tile, K=128 fully staged, 4 waves each computing a 64x64 sub-tile.
// LDS granule g (8 bf16, 16B) of row r stored at physical slot g ^ (r&7)  (T2 swizzle).

__global__ __launch_bounds__(256) void gemm1_kernel(const float* __restrict__ x,
                                                    const ushort* __restrict__ W1T,
                                                    const float* __restrict__ a_src,
                                                    const float* __restrict__ a_dst,
                                                    uint32_t* __restrict__ h1,
                                                    float* __restrict__ asrc1,
                                                    float* __restrict__ adst1, int N) {
    __shared__ __align__(16) ushort As[128][128];
    __shared__ __align__(16) ushort Bs[128][128];
    int tid = threadIdx.x;
    int c0 = blockIdx.x * 128;     // col block (fastest-varying -> x-tile L2 reuse)
    int row0 = blockIdx.y * 128;   // row block

    {   // stage A (fp32 x -> bf16) and B (bf16 W1T), swizzled
        int g = tid & 15;       // granule
        int r4 = tid >> 4;      // 0..15
        #pragma unroll
        for (int pass = 0; pass < 8; ++pass) {
            int r = r4 + pass * 16;
            int gr = row0 + r;
            float4 v0 = make_float4(0.f, 0.f, 0.f, 0.f), v1 = v0;
            if (gr < N) {
                v0 = *(const float4*)(x + (size_t)gr * 128 + g * 8);
                v1 = *(const float4*)(x + (size_t)gr * 128 + g * 8 + 4);
            }
            uint4 pk = make_uint4(pack_bf2(v0.x, v0.y), pack_bf2(v0.z, v0.w),
                                  pack_bf2(v1.x, v1.y), pack_bf2(v1.z, v1.w));
            *(uint4*)&As[r][(g ^ (r & 7)) * 8] = pk;
        }
        #pragma unroll
        for (int pass = 0; pass < 8; ++pass) {
            int r = r4 + pass * 16;
            uint4 q = *(const uint4*)(W1T + (size_t)(c0 + r) * 128 + g * 8);
            *(uint4*)&Bs[r][(g ^ (r & 7)) * 8] = q;
        }
    }
    __syncthreads();

    int wave = tid >> 6, lane = tid & 63;
    int wr = wave >> 1, wc = wave & 1;
    int lg = lane >> 4, lr = lane & 15;

    f32x4 acc[4][4] = {};
    #pragma unroll
    for (int kk = 0; kk < 4; ++kk) {
        bf16x8 a[4], b[4];
        int gk = kk * 4 + lg;
        #pragma unroll
        for (int mi = 0; mi < 4; ++mi) {
            int r = wr * 64 + mi * 16 + lr;
            a[mi] = *(const bf16x8*)&As[r][(gk ^ (r & 7)) * 8];
        }
        #pragma unroll
        for (int nj = 0; nj < 4; ++nj) {
            int r = wc * 64 + nj * 16 + lr;
            b[nj] = *(const bf16x8*)&Bs[r][(gk ^ (r & 7)) * 8];
        }
        #pragma unroll
        for (int mi = 0; mi < 4; ++mi)
            #pragma unroll
            for (int nj = 0; nj < 4; ++nj)
                acc[mi][nj] = __builtin_amdgcn_mfma_f32_16x16x32_bf16(
                    a[mi], b[nj], acc[mi][nj], 0, 0, 0);
    }

    // ---- epilogue: alpha dots + bf16 pack. D mapping: col=lr, row=lg*4+reg.
    int hh = blockIdx.x * 2 + wc;  // head for this wave's 64 cols
    float as4[4], ad4[4];
    #pragma unroll
    for (int nj = 0; nj < 4; ++nj) {
        as4[nj] = a_src[hh * 64 + nj * 16 + lr];
        ad4[nj] = a_dst[hh * 64 + nj * 16 + lr];
    }
    #pragma unroll
    for (int mi = 0; mi < 4; ++mi) {
        #pragma unroll
        for (int reg = 0; reg < 4; ++reg) {
            int row = row0 + wr * 64 + mi * 16 + lg * 4 + reg;
            float v0 = acc[mi][0][reg], v1 = acc[mi][1][reg];
            float v2 = acc[mi][2][reg], v3 = acc[mi][3][reg];
            float ps = v0 * as4[0] + v1 * as4[1] + v2 * as4[2] + v3 * as4[3];
            float pd = v0 * ad4[0] + v1 * ad4[1] + v2 * ad4[2] + v3 * ad4[3];
            #pragma unroll
            for (int m = 1; m < 16; m <<= 1) {
                ps += __shfl_xor(ps, m);
                pd += __shfl_xor(pd, m);
            }
            bool store_row = (row < N);
            if (store_row && lr == 0) {
                asrc1[(size_t)row * 8 + hh] = ps;
                adst1[(size_t)row * 8 + hh] = pd;
            }
            // pack adjacent columns (lr even pairs with lr+1)
            float p0 = __shfl_xor(v0, 1), p1 = __shfl_xor(v1, 1);
            float p2 = __shfl_xor(v2, 1), p3 = __shfl_xor(v3, 1);
            if (store_row && (lr & 1) == 0) {
                size_t base = (size_t)row * 256 + ((c0 + wc * 64 + lr) >> 1);
                h1[base + 0]  = pack_bf2(v0, p0);
                h1[base + 8]  = pack_bf2(v1, p1);
                h1[base + 16] = pack_bf2(v2, p2);
                h1[base + 24] = pack_bf2(v3, p3);
            }
        }
    }
}

// ---------------- Layer 1 aggregation (one wave per node, bf16 h1) ----------------

__global__ __launch_bounds__(256) void agg1_kernel(const uint32_t* __restrict__ h1,
                                                   const float* __restrict__ asrc,
                                                   const float* __restrict__ adst,
                                                   const int* __restrict__ off,
                                                   const int* __restrict__ csr_src,
                                                   const float* __restrict__ b1,
                                                   uint32_t* __restrict__ out1, int N) {
    int n = (blockIdx.x * blockDim.x + threadIdx.x) >> 6;
    int lane = threadIdx.x & 63;
    if (n >= N) return;
    int hi = lane >> 5;
    int cl = (lane & 31) * 2;
    float ad[4], d[4];
    float2 acc[4];
    #pragma unroll
    for (int k = 0; k < 4; ++k) ad[k] = adst[(size_t)n * 8 + 2 * k + hi];
    {   // self loop
        const uint32_t* hrow = h1 + (size_t)n * 256;
        #pragma unroll
        for (int k = 0; k < 4; ++k) {
            float e = asrc[(size_t)n * 8 + 2 * k + hi] + ad[k];
            float w = __expf(LEAKY(e));
            d[k] = w;
            float2 hv = bf2_to_f2(hrow[k * 64 + lane]);
            acc[k].x = w * hv.x;
            acc[k].y = w * hv.y;
        }
    }
    int t = off[n], tend = off[n + 1];
    for (; t + 1 < tend; t += 2) {
        int s0 = csr_src[t], s1 = csr_src[t + 1];
        const uint32_t* hr0 = h1 + (size_t)s0 * 256;
        const uint32_t* hr1 = h1 + (size_t)s1 * 256;
        uint32_t p0[4], p1[4];
        float e0[4], e1[4];
        #pragma unroll
        for (int k = 0; k < 4; ++k) { p0[k] = hr0[k * 64 + lane]; p1[k] = hr1[k * 64 + lane]; }
        #pragma unroll
        for (int k = 0; k < 4; ++k) {
            e0[k] = asrc[(size_t)s0 * 8 + 2 * k + hi] + ad[k];
            e1[k] = asrc[(size_t)s1 * 8 + 2 * k + hi] + ad[k];
        }
        #pragma unroll
        for (int k = 0; k < 4; ++k) {
            float w0 = __expf(LEAKY(e0[k]));
            float w1 = __expf(LEAKY(e1[k]));
            d[k] += w0 + w1;
            float2 h0 = bf2_to_f2(p0[k]), h1v = bf2_to_f2(p1[k]);
            acc[k].x += w0 * h0.x + w1 * h1v.x;
            acc[k].y += w0 * h0.y + w1 * h1v.y;
        }
    }
    if (t < tend) {
        int s = csr_src[t];
        const uint32_t* hr = h1 + (size_t)s * 256;
        #pragma unroll
        for (int k = 0; k < 4; ++k) {
            float e = asrc[(size_t)s * 8 + 2 * k + hi] + ad[k];
            float w = __expf(LEAKY(e));
            d[k] += w;
            float2 hv = bf2_to_f2(hr[k * 64 + lane]);
            acc[k].x += w * hv.x;
            acc[k].y += w * hv.y;
        }
    }
    #pragma unroll
    for (int k = 0; k < 4; ++k) {
        int head = 2 * k + hi;
        float2 bv = *(const float2*)(b1 + head * 64 + cl);
        float inv = 1.f / (d[k] + 1e-16f);
        float ox = fmaxf(acc[k].x * inv + bv.x, 0.f);
        float oy = fmaxf(acc[k].y * inv + bv.y, 0.f);
        out1[(size_t)n * 256 + k * 64 + lane] = pack_bf2(ox, oy);
    }
}

// ------- Layer 2 GEMM + alpha2: h2 = out1 @ W2 ([N,512(bf16)]@[512,8]) -------

__global__ __launch_bounds__(512) void gemm2_kernel(const uint32_t* __restrict__ out1,
                                                    const float* __restrict__ W2,
                                                    const float* __restrict__ a_src2,
                                                    const float* __restrict__ a_dst2,
                                                    float* __restrict__ h2,
                                                    float* __restrict__ as2,
                                                    float* __restrict__ ad2, int N) {
    __shared__ __align__(16) float xs[64][65];
    __shared__ __align__(16) float w2s[512 * 8];
    int tid = threadIdx.x;
    int node0 = blockIdx.x * 64;
    for (int i = tid; i < 1024; i += 512) ((float4*)w2s)[i] = ((const float4*)W2)[i];
    int r = tid >> 3, c = tid & 7;
    float acc = 0.f;
    for (int kb = 0; kb < 8; ++kb) {
        __syncthreads();
        #pragma unroll
        for (int li = 0; li < 2; ++li) {
            int f4 = tid + li * 512;
            int rr = f4 >> 4, q = f4 & 15;
            int gr = node0 + rr;
            uint2 pv = make_uint2(0u, 0u);
            if (gr < N) pv = *(const uint2*)(out1 + (size_t)gr * 256 + kb * 32 + q * 2);
            float2 v0 = bf2_to_f2(pv.x), v1 = bf2_to_f2(pv.y);
            float* dsti = &xs[rr][q * 4];
            dsti[0] = v0.x; dsti[1] = v0.y; dsti[2] = v1.x; dsti[3] = v1.y;
        }
        __syncthreads();
        #pragma unroll 8
        for (int k = 0; k < 64; ++k)
            acc += xs[r][k] * w2s[(kb * 64 + k) * 8 + c];
    }
    float pa = acc * a_src2[c];
    float pb = acc * a_dst2[c];
    #pragma unroll
    for (int d2 = 1; d2 < 8; d2 <<= 1) {
        pa += __shfl_xor(pa, d2);
        pb += __shfl_xor(pb, d2);
    }
    int n = node0 + r;
    if (n < N) {
        h2[(size_t)n * 8 + c] = acc;
        if (c == 0) { as2[n] = pa; ad2[n] = pb; }
    }
}

// ---------------- Layer 2 aggregation (8 lanes per node) + bias ----------------

__global__ __launch_bounds__(256) void agg2_kernel(const float* __restrict__ h2,
                                                   const float* __restrict__ as2,
                                                   const float* __restrict__ ad2,
                                                   const int* __restrict__ off,
                                                   const int* __restrict__ csr_src,
                                                   const float* __restrict__ b2,
                                                   float* __restrict__ out, int N) {
    int gid = blockIdx.x * blockDim.x + threadIdx.x;
    int n = gid >> 3, c = gid & 7;
    if (n >= N) return;
    float adn = ad2[n];
    float e = LEAKY(as2[n] + adn);
    float w = __expf(e);
    float d = w;
    float acc = w * h2[(size_t)n * 8 + c];
    int t0e = off[n], t1e = off[n + 1];
    for (int t = t0e; t < t1e; ++t) {
        int s = csr_src[t];
        float ee = LEAKY(as2[s] + adn);
        float ws = __expf(ee);
        d += ws;
        acc += ws * h2[(size_t)s * 8 + c];
    }
    out[(size_t)n * 8 + c] = acc / (d + 1e-16f) + b2[c];
}

// ---------------- launcher ----------------

extern "C" void kernel_launch(void* const* d_in, const int* in_sizes, int n_in,
                              void* d_out, int out_size, void* d_ws, size_t ws_size,
                              hipStream_t stream) {
    const float* x      = (const float*)d_in[0];
    const int*   ei     = (const int*)d_in[1];
    const float* W1     = (const float*)d_in[2];
    const float* a_src1 = (const float*)d_in[3];
    const float* a_dst1 = (const float*)d_in[4];
    const float* b1     = (const float*)d_in[5];
    const float* W2     = (const float*)d_in[6];
    const float* a_src2 = (const float*)d_in[7];
    const float* a_dst2 = (const float*)d_in[8];
    const float* b2     = (const float*)d_in[9];

    int N = in_sizes[0] / 128;
    int E = in_sizes[1] / 2;
    const int* src = ei;
    const int* dst = ei + E;

    char* w = (char*)d_ws;
    size_t o = 0;
    auto alloc = [&](size_t bytes) {
        void* p = w + o;
        o = (o + bytes + 255) & ~(size_t)255;
        return p;
    };
    uint32_t* h1     = (uint32_t*)alloc((size_t)N * 256 * 4);  // bf16 [N,512]
    uint32_t* out1   = (uint32_t*)alloc((size_t)N * 256 * 4);  // bf16 [N,512]
    float*    asrc1  = (float*)alloc((size_t)N * 8 * 4);
    float*    adst1  = (float*)alloc((size_t)N * 8 * 4);
    float*    h2     = (float*)alloc((size_t)N * 8 * 4);
    float*    as2    = (float*)alloc((size_t)N * 4);
    float*    ad2    = (float*)alloc((size_t)N * 4);
    int*      deg    = (int*)alloc((size_t)N * 4);
    int*      offb   = (int*)alloc((size_t)(N + 1) * 4);
    int*      cursor = (int*)alloc((size_t)N * 4);
    int*      csrs   = (int*)alloc((size_t)E * 4);
    ushort*   W1T    = (ushort*)alloc((size_t)512 * 128 * 2);

    hipMemsetAsync(deg, 0, (size_t)N * 4, stream);
    hipMemsetAsync(cursor, 0, (size_t)N * 4, stream);

    degree_kernel<<<(E + 255) / 256, 256, 0, stream>>>(dst, deg, E);
    scan_kernel<<<1, 1024, 0, stream>>>(deg, offb, N);
    scatter_kernel<<<(E + 255) / 256, 256, 0, stream>>>(src, dst, offb, cursor, csrs, E);

    w1t_kernel<<<8, 256, 0, stream>>>(W1, W1T);
    gemm1_kernel<<<dim3(4, (N + 127) / 128), 256, 0, stream>>>(x, W1T, a_src1, a_dst1,
                                                               h1, asrc1, adst1, N);
    agg1_kernel<<<((size_t)N * 64 + 255) / 256, 256, 0, stream>>>(h1, asrc1, adst1, offb,
                                                                  csrs, b1, out1, N);

    gemm2_kernel<<<(N + 63) / 64, 512, 0, stream>>>(out1, W2, a_src2, a_dst2, h2, as2, ad2, N);
    agg2_kernel<<<((size_t)N * 8 + 255) / 256, 256, 0, stream>>>(h2, as2, ad2, offb, csrs, b2,
                                                                 (float*)d_out, N);
}

// Round 7
// 271.794 us; speedup vs baseline: 1.6069x; 1.0806x over previous
//
#include <hip/hip_runtime.h>
#include <stdint.h>

#define LEAKY(x) ((x) > 0.f ? (x) : 0.2f * (x))

typedef short bf16x8 __attribute__((ext_vector_type(8)));
typedef float f32x4 __attribute__((ext_vector_type(4)));

__device__ inline float2 bf2_to_f2(uint32_t p) {
    return make_float2(__uint_as_float(p << 16), __uint_as_float(p & 0xffff0000u));
}
__device__ inline uint32_t pack_bf2(float x, float y) {
    uint32_t xb = __float_as_uint(x), yb = __float_as_uint(y);
    xb += 0x7fff + ((xb >> 16) & 1);   // RNE to bf16
    yb += 0x7fff + ((yb >> 16) & 1);
    return (xb >> 16) | (yb & 0xffff0000u);
}
__device__ inline ushort to_bf16(float v) {
    uint32_t b = __float_as_uint(v);
    b += 0x7fff + ((b >> 16) & 1);
    return (ushort)(b >> 16);
}

// ---------------- CSR build ----------------

__global__ void degree_kernel(const int* __restrict__ dst, int* __restrict__ deg, int E) {
    int e = blockIdx.x * blockDim.x + threadIdx.x;
    if (e < E) atomicAdd(&deg[dst[e]], 1);
}

__global__ __launch_bounds__(1024) void scan_kernel(const int* __restrict__ deg,
                                                    int* __restrict__ off, int n) {
    __shared__ int wsum[16];
    int tid = threadIdx.x;
    int lane = tid & 63, wid = tid >> 6;
    int carry = 0;
    for (int base = 0; base < n; base += 1024) {
        int i = base + tid;
        int v = (i < n) ? deg[i] : 0;
        int x = v;
        #pragma unroll
        for (int d2 = 1; d2 < 64; d2 <<= 1) {
            int y = __shfl_up(x, d2);
            if (lane >= d2) x += y;
        }
        if (lane == 63) wsum[wid] = x;
        __syncthreads();
        if (tid < 16) {
            int s = wsum[tid];
            #pragma unroll
            for (int d2 = 1; d2 < 16; d2 <<= 1) {
                int y = __shfl_up(s, d2, 16);
                if (tid >= d2) s += y;
            }
            wsum[tid] = s;
        }
        __syncthreads();
        int wbase = wid ? wsum[wid - 1] : 0;
        int total = wsum[15];
        if (i < n) off[i] = carry + wbase + (x - v);  // exclusive
        carry += total;
        __syncthreads();
    }
    if (tid == 0) off[n] = carry;
}

__global__ void scatter_kernel(const int* __restrict__ src, const int* __restrict__ dst,
                               const int* __restrict__ off, int* __restrict__ cursor,
                               int* __restrict__ csr_src, int E) {
    int e = blockIdx.x * blockDim.x + threadIdx.x;
    if (e < E) {
        int d = dst[e];
        int p = atomicAdd(&cursor[d], 1);
        csr_src[off[d] + p] = src[e];
    }
}

// ---------------- W1 -> W1T bf16 [512][128] ----------------

__global__ __launch_bounds__(256) void w1t_kernel(const float* __restrict__ W,
                                                  ushort* __restrict__ WT) {
    int c = blockIdx.x * 64 + (threadIdx.x & 63);
    int k0 = (threadIdx.x >> 6) * 32;
    #pragma unroll
    for (int j = 0; j < 32; ++j)
        WT[(size_t)c * 128 + k0 + j] = to_bf16(W[(size_t)(k0 + j) * 512 + c]);
}

// ------- Layer 1 GEMM via MFMA: h1 = x @ W1 ([N,128]@[128,512]) + fused alphas -------
// 128x128 tile, K=128 fully staged, 4 waves each computing a 64x64 sub-tile.
// LDS granule g (8 bf16, 16B) of row r stored at physical slot g ^ (r&7)  (T2 swizzle).

__global__ __launch_bounds__(256) void gemm1_kernel(const float* __restrict__ x,
                                                    const ushort* __restrict__ W1T,
                                                    const float* __restrict__ a_src,
                                                    const float* __restrict__ a_dst,
                                                    uint32_t* __restrict__ h1,
                                                    float* __restrict__ asrc1,
                                                    float* __restrict__ adst1, int N) {
    __shared__ __align__(16) ushort As[128][128];
    __shared__ __align__(16) ushort Bs[128][128];
    int tid = threadIdx.x;
    int c0 = blockIdx.x * 128;     // col block (fastest-varying -> x-tile L2 reuse)
    int row0 = blockIdx.y * 128;   // row block

    {   // stage A (fp32 x -> bf16) and B (bf16 W1T), swizzled
        int g = tid & 15;       // granule
        int r4 = tid >> 4;      // 0..15
        #pragma unroll
        for (int pass = 0; pass < 8; ++pass) {
            int r = r4 + pass * 16;
            int gr = row0 + r;
            float4 v0 = make_float4(0.f, 0.f, 0.f, 0.f), v1 = v0;
            if (gr < N) {
                v0 = *(const float4*)(x + (size_t)gr * 128 + g * 8);
                v1 = *(const float4*)(x + (size_t)gr * 128 + g * 8 + 4);
            }
            uint4 pk = make_uint4(pack_bf2(v0.x, v0.y), pack_bf2(v0.z, v0.w),
                                  pack_bf2(v1.x, v1.y), pack_bf2(v1.z, v1.w));
            *(uint4*)&As[r][(g ^ (r & 7)) * 8] = pk;
        }
        #pragma unroll
        for (int pass = 0; pass < 8; ++pass) {
            int r = r4 + pass * 16;
            uint4 q = *(const uint4*)(W1T + (size_t)(c0 + r) * 128 + g * 8);
            *(uint4*)&Bs[r][(g ^ (r & 7)) * 8] = q;
        }
    }
    __syncthreads();

    int wave = tid >> 6, lane = tid & 63;
    int wr = wave >> 1, wc = wave & 1;
    int lg = lane >> 4, lr = lane & 15;

    f32x4 acc[4][4] = {};
    #pragma unroll
    for (int kk = 0; kk < 4; ++kk) {
        bf16x8 a[4], b[4];
        int gk = kk * 4 + lg;
        #pragma unroll
        for (int mi = 0; mi < 4; ++mi) {
            int r = wr * 64 + mi * 16 + lr;
            a[mi] = *(const bf16x8*)&As[r][(gk ^ (r & 7)) * 8];
        }
        #pragma unroll
        for (int nj = 0; nj < 4; ++nj) {
            int r = wc * 64 + nj * 16 + lr;
            b[nj] = *(const bf16x8*)&Bs[r][(gk ^ (r & 7)) * 8];
        }
        #pragma unroll
        for (int mi = 0; mi < 4; ++mi)
            #pragma unroll
            for (int nj = 0; nj < 4; ++nj)
                acc[mi][nj] = __builtin_amdgcn_mfma_f32_16x16x32_bf16(
                    a[mi], b[nj], acc[mi][nj], 0, 0, 0);
    }

    // ---- epilogue: alpha dots + bf16 pack. D mapping: col=lr, row=lg*4+reg.
    int hh = blockIdx.x * 2 + wc;  // head for this wave's 64 cols
    float as4[4], ad4[4];
    #pragma unroll
    for (int nj = 0; nj < 4; ++nj) {
        as4[nj] = a_src[hh * 64 + nj * 16 + lr];
        ad4[nj] = a_dst[hh * 64 + nj * 16 + lr];
    }
    #pragma unroll
    for (int mi = 0; mi < 4; ++mi) {
        #pragma unroll
        for (int reg = 0; reg < 4; ++reg) {
            int row = row0 + wr * 64 + mi * 16 + lg * 4 + reg;
            float v0 = acc[mi][0][reg], v1 = acc[mi][1][reg];
            float v2 = acc[mi][2][reg], v3 = acc[mi][3][reg];
            float ps = v0 * as4[0] + v1 * as4[1] + v2 * as4[2] + v3 * as4[3];
            float pd = v0 * ad4[0] + v1 * ad4[1] + v2 * ad4[2] + v3 * ad4[3];
            #pragma unroll
            for (int m = 1; m < 16; m <<= 1) {
                ps += __shfl_xor(ps, m);
                pd += __shfl_xor(pd, m);
            }
            bool store_row = (row < N);
            if (store_row && lr == 0) {
                asrc1[(size_t)row * 8 + hh] = ps;
                adst1[(size_t)row * 8 + hh] = pd;
            }
            // pack adjacent columns (lr even pairs with lr+1)
            float p0 = __shfl_xor(v0, 1), p1 = __shfl_xor(v1, 1);
            float p2 = __shfl_xor(v2, 1), p3 = __shfl_xor(v3, 1);
            if (store_row && (lr & 1) == 0) {
                size_t base = (size_t)row * 256 + ((c0 + wc * 64 + lr) >> 1);
                h1[base + 0]  = pack_bf2(v0, p0);
                h1[base + 8]  = pack_bf2(v1, p1);
                h1[base + 16] = pack_bf2(v2, p2);
                h1[base + 24] = pack_bf2(v3, p3);
            }
        }
    }
}

// ---------------- Layer 1 aggregation (one wave per node, bf16 h1) ----------------
// Lane l owns contiguous channels [8l, 8l+8) -> single head (l>>3): 1 exp + 1
// dwordx4 per lane per edge; denominator is lane-local.

__global__ __launch_bounds__(256) void agg1_kernel(const uint4* __restrict__ h1,
                                                   const float* __restrict__ asrc,
                                                   const float* __restrict__ adst,
                                                   const int* __restrict__ off,
                                                   const int* __restrict__ csr_src,
                                                   const float* __restrict__ b1,
                                                   uint4* __restrict__ out1, int N) {
    int n = (blockIdx.x * blockDim.x + threadIdx.x) >> 6;
    int lane = threadIdx.x & 63;
    if (n >= N) return;
    int hd = lane >> 3;
    float ad = adst[(size_t)n * 8 + hd];
    float acc[8];
    float d;
    {   // self loop
        float w = __expf(LEAKY(asrc[(size_t)n * 8 + hd] + ad));
        d = w;
        uint4 p = h1[(size_t)n * 64 + lane];
        float2 c0 = bf2_to_f2(p.x), c1 = bf2_to_f2(p.y);
        float2 c2 = bf2_to_f2(p.z), c3 = bf2_to_f2(p.w);
        acc[0] = w * c0.x; acc[1] = w * c0.y; acc[2] = w * c1.x; acc[3] = w * c1.y;
        acc[4] = w * c2.x; acc[5] = w * c2.y; acc[6] = w * c3.x; acc[7] = w * c3.y;
    }
    auto addp = [&](uint4 p, float w) {
        float2 c0 = bf2_to_f2(p.x), c1 = bf2_to_f2(p.y);
        float2 c2 = bf2_to_f2(p.z), c3 = bf2_to_f2(p.w);
        d += w;
        acc[0] += w * c0.x; acc[1] += w * c0.y; acc[2] += w * c1.x; acc[3] += w * c1.y;
        acc[4] += w * c2.x; acc[5] += w * c2.y; acc[6] += w * c3.x; acc[7] += w * c3.y;
    };
    int t = off[n], tend = off[n + 1];
    for (; t + 3 < tend; t += 4) {
        int s0 = csr_src[t], s1 = csr_src[t + 1];
        int s2 = csr_src[t + 2], s3 = csr_src[t + 3];
        uint4 p0 = h1[(size_t)s0 * 64 + lane];
        uint4 p1 = h1[(size_t)s1 * 64 + lane];
        uint4 p2 = h1[(size_t)s2 * 64 + lane];
        uint4 p3 = h1[(size_t)s3 * 64 + lane];
        float w0 = __expf(LEAKY(asrc[(size_t)s0 * 8 + hd] + ad));
        float w1 = __expf(LEAKY(asrc[(size_t)s1 * 8 + hd] + ad));
        float w2 = __expf(LEAKY(asrc[(size_t)s2 * 8 + hd] + ad));
        float w3 = __expf(LEAKY(asrc[(size_t)s3 * 8 + hd] + ad));
        addp(p0, w0); addp(p1, w1); addp(p2, w2); addp(p3, w3);
    }
    for (; t < tend; ++t) {
        int s = csr_src[t];
        uint4 p = h1[(size_t)s * 64 + lane];
        float w = __expf(LEAKY(asrc[(size_t)s * 8 + hd] + ad));
        addp(p, w);
    }
    float inv = 1.f / (d + 1e-16f);
    float4 b0 = *(const float4*)(b1 + lane * 8);
    float4 b4 = *(const float4*)(b1 + lane * 8 + 4);
    float o0 = fmaxf(acc[0] * inv + b0.x, 0.f);
    float o1 = fmaxf(acc[1] * inv + b0.y, 0.f);
    float o2 = fmaxf(acc[2] * inv + b0.z, 0.f);
    float o3 = fmaxf(acc[3] * inv + b0.w, 0.f);
    float o4 = fmaxf(acc[4] * inv + b4.x, 0.f);
    float o5 = fmaxf(acc[5] * inv + b4.y, 0.f);
    float o6 = fmaxf(acc[6] * inv + b4.z, 0.f);
    float o7 = fmaxf(acc[7] * inv + b4.w, 0.f);
    uint4 q;
    q.x = pack_bf2(o0, o1); q.y = pack_bf2(o2, o3);
    q.z = pack_bf2(o4, o5); q.w = pack_bf2(o6, o7);
    out1[(size_t)n * 64 + lane] = q;
}

// ------- Layer 2 GEMM + alpha2: h2 = out1 @ W2 ([N,512(bf16)]@[512,8]) -------
// One wave per 8 rows; lane = (row&7 chunk of 64 channels); W2 in padded LDS
// (chunk stride 2064B -> broadcast groups land on banks {0,4,..,28}: conflict-free).

__global__ __launch_bounds__(256) void gemm2_kernel(const uint4* __restrict__ out1,
                                                    const float* __restrict__ W2,
                                                    const float* __restrict__ a_src2,
                                                    const float* __restrict__ a_dst2,
                                                    float* __restrict__ h2,
                                                    float* __restrict__ as2,
                                                    float* __restrict__ ad2, int N) {
    __shared__ __align__(16) float w2s[8][64 * 8 + 4];
    int tid = threadIdx.x;
    #pragma unroll
    for (int j = 0; j < 4; ++j) {
        int i4 = tid * 4 + j;              // 0..1023 float4s of W2
        float4 v = ((const float4*)W2)[i4];
        int k = i4 >> 1;                   // 0..511
        int half = (i4 & 1) * 4;
        *(float4*)&w2s[k >> 6][(k & 63) * 8 + half] = v;
    }
    __syncthreads();
    int lane = tid & 63, wave = tid >> 6;
    int row = blockIdx.x * 32 + wave * 8 + (lane >> 3);
    int chunk = lane & 7;
    float acc[8] = {};
    if (row < N) {
        const uint4* xr = out1 + (size_t)row * 64 + chunk * 8;
        #pragma unroll
        for (int j = 0; j < 8; ++j) {
            uint4 p = xr[j];
            float2 c0 = bf2_to_f2(p.x), c1 = bf2_to_f2(p.y);
            float2 c2 = bf2_to_f2(p.z), c3 = bf2_to_f2(p.w);
            float xv[8] = {c0.x, c0.y, c1.x, c1.y, c2.x, c2.y, c3.x, c3.y};
            const float* wrow = &w2s[chunk][j * 64];
            #pragma unroll
            for (int i = 0; i < 8; ++i) {
                float4 wa = *(const float4*)(wrow + i * 8);
                float4 wb = *(const float4*)(wrow + i * 8 + 4);
                acc[0] += xv[i] * wa.x; acc[1] += xv[i] * wa.y;
                acc[2] += xv[i] * wa.z; acc[3] += xv[i] * wa.w;
                acc[4] += xv[i] * wb.x; acc[5] += xv[i] * wb.y;
                acc[6] += xv[i] * wb.z; acc[7] += xv[i] * wb.w;
            }
        }
    }
    #pragma unroll
    for (int m = 1; m < 8; m <<= 1)
        #pragma unroll
        for (int c = 0; c < 8; ++c)
            acc[c] += __shfl_xor(acc[c], m);
    if (row < N) {
        float pa = 0.f, pb = 0.f;
        #pragma unroll
        for (int c = 0; c < 8; ++c) { pa += acc[c] * a_src2[c]; pb += acc[c] * a_dst2[c]; }
        float myv = 0.f;
        #pragma unroll
        for (int c = 0; c < 8; ++c) if (chunk == c) myv = acc[c];
        h2[(size_t)row * 8 + chunk] = myv;
        if (chunk == 0) { as2[row] = pa; ad2[row] = pb; }
    }
}

// ---------------- Layer 2 aggregation (8 lanes per node) + bias ----------------

__global__ __launch_bounds__(256) void agg2_kernel(const float* __restrict__ h2,
                                                   const float* __restrict__ as2,
                                                   const float* __restrict__ ad2,
                                                   const int* __restrict__ off,
                                                   const int* __restrict__ csr_src,
                                                   const float* __restrict__ b2,
                                                   float* __restrict__ out, int N) {
    int gid = blockIdx.x * blockDim.x + threadIdx.x;
    int n = gid >> 3, c = gid & 7;
    if (n >= N) return;
    float adn = ad2[n];
    float e = LEAKY(as2[n] + adn);
    float w = __expf(e);
    float d = w;
    float acc = w * h2[(size_t)n * 8 + c];
    int t0e = off[n], t1e = off[n + 1];
    for (int t = t0e; t < t1e; ++t) {
        int s = csr_src[t];
        float ee = LEAKY(as2[s] + adn);
        float ws = __expf(ee);
        d += ws;
        acc += ws * h2[(size_t)s * 8 + c];
    }
    out[(size_t)n * 8 + c] = acc / (d + 1e-16f) + b2[c];
}

// ---------------- launcher ----------------

extern "C" void kernel_launch(void* const* d_in, const int* in_sizes, int n_in,
                              void* d_out, int out_size, void* d_ws, size_t ws_size,
                              hipStream_t stream) {
    const float* x      = (const float*)d_in[0];
    const int*   ei     = (const int*)d_in[1];
    const float* W1     = (const float*)d_in[2];
    const float* a_src1 = (const float*)d_in[3];
    const float* a_dst1 = (const float*)d_in[4];
    const float* b1     = (const float*)d_in[5];
    const float* W2     = (const float*)d_in[6];
    const float* a_src2 = (const float*)d_in[7];
    const float* a_dst2 = (const float*)d_in[8];
    const float* b2     = (const float*)d_in[9];

    int N = in_sizes[0] / 128;
    int E = in_sizes[1] / 2;
    const int* src = ei;
    const int* dst = ei + E;

    char* w = (char*)d_ws;
    size_t o = 0;
    auto alloc = [&](size_t bytes) {
        void* p = w + o;
        o = (o + bytes + 255) & ~(size_t)255;
        return p;
    };
    uint32_t* h1     = (uint32_t*)alloc((size_t)N * 256 * 4);  // bf16 [N,512]
    uint32_t* out1   = (uint32_t*)alloc((size_t)N * 256 * 4);  // bf16 [N,512]
    float*    asrc1  = (float*)alloc((size_t)N * 8 * 4);
    float*    adst1  = (float*)alloc((size_t)N * 8 * 4);
    float*    h2     = (float*)alloc((size_t)N * 8 * 4);
    float*    as2    = (float*)alloc((size_t)N * 4);
    float*    ad2    = (float*)alloc((size_t)N * 4);
    int*      deg    = (int*)alloc((size_t)N * 4);
    int*      offb   = (int*)alloc((size_t)(N + 1) * 4);
    int*      cursor = (int*)alloc((size_t)N * 4);
    int*      csrs   = (int*)alloc((size_t)E * 4);
    ushort*   W1T    = (ushort*)alloc((size_t)512 * 128 * 2);

    hipMemsetAsync(deg, 0, (size_t)N * 4, stream);
    hipMemsetAsync(cursor, 0, (size_t)N * 4, stream);

    degree_kernel<<<(E + 255) / 256, 256, 0, stream>>>(dst, deg, E);
    scan_kernel<<<1, 1024, 0, stream>>>(deg, offb, N);
    scatter_kernel<<<(E + 255) / 256, 256, 0, stream>>>(src, dst, offb, cursor, csrs, E);

    w1t_kernel<<<8, 256, 0, stream>>>(W1, W1T);
    gemm1_kernel<<<dim3(4, (N + 127) / 128), 256, 0, stream>>>(x, W1T, a_src1, a_dst1,
                                                               h1, asrc1, adst1, N);
    agg1_kernel<<<((size_t)N * 64 + 255) / 256, 256, 0, stream>>>((const uint4*)h1, asrc1,
                                                                  adst1, offb, csrs, b1,
                                                                  (uint4*)out1, N);

    gemm2_kernel<<<(N + 31) / 32, 256, 0, stream>>>((const uint4*)out1, W2, a_src2, a_dst2,
                                                    h2, as2, ad2, N);
    agg2_kernel<<<((size_t)N * 8 + 255) / 256, 256, 0, stream>>>(h2, as2, ad2, offb, csrs, b2,
                                                                 (float*)d_out, N);
}